// Round 4
// baseline (31.851 us; speedup 1.0000x reference)
//
#include <hip/hip_runtime.h>

// SNNMaxPool2d winner-take-all forward, 256B-granule-aligned sparse probe.
// x: [B=4, C=32, H=64, W=64, T=100] f32 spikes. out: [4,32,32,32,100] one-hot
// of earliest spiking t per 2x2/stride-2 window.
//
// One wave64 per window. 4 cells x 16 lanes x float4: each cell's probe is
// exactly the 256B-aligned granule containing its t=0 (timing-fit across
// R1-R3 indicates 256B effective HBM fetch granularity, so this costs the
// same traffic as a 128B probe but covers up to 64 timesteps/cell).
// Probe min-t valid iff < min coverage over cells; else (~0.2%) dense rescan.

#define T_DIM 100

__global__ __launch_bounds__(256) void snn_wta_kernel(
    const float* __restrict__ x, float* __restrict__ out, int n_pix)
{
    const int T = T_DIM;
    const int C = 32, H = 64, W = 64, OH = 32, OW = 32;

    const int wave = threadIdx.x >> 6;   // 0..3
    const int lane = threadIdx.x & 63;
    const int cell = lane >> 4;          // 0..3 window cell
    const int q    = lane & 15;          // lane within cell (16 x float4 = 256B)

    const int p = blockIdx.x * 4 + wave;
    if (p >= n_pix) return;

    const int ow = p & (OW - 1);
    int tmp = p >> 5;
    const int oh = tmp & (OH - 1);
    tmp >>= 5;
    const int c = tmp & (C - 1);
    const int b = tmp >> 5;

    const size_t base0 = ((((size_t)b * C + c) * H + oh * 2) * W + ow * 2) * T;
    const float* __restrict__ r0 = x + base0;          // (h,w) then (h,w+1)
    const float* __restrict__ A  = r0
        + ((cell & 2) ? (size_t)W * T : 0)
        + ((cell & 1) ? T : 0);

    // 256B-aligned granule containing this cell's t=0
    const float* __restrict__ Ad =
        (const float*)((uintptr_t)A & ~(uintptr_t)255);
    const int moff = (int)(((uintptr_t)A & 255) >> 2);   // junk floats before t=0 (0..63)
    const float4 v = *(const float4*)(Ad + q * 4);
    const int t0 = q * 4 - moff;                         // in [-63, 63] < T

    int lmint = T;
    if (t0 + 0 >= 0 && v.x > 0.0f) lmint = min(lmint, t0 + 0);
    if (t0 + 1 >= 0 && v.y > 0.0f) lmint = min(lmint, t0 + 1);
    if (t0 + 2 >= 0 && v.z > 0.0f) lmint = min(lmint, t0 + 2);
    if (t0 + 3 >= 0 && v.w > 0.0f) lmint = min(lmint, t0 + 3);

    // full-wave min-reduce
    #pragma unroll
    for (int off = 32; off >= 1; off >>= 1)
        lmint = min(lmint, __shfl_xor(lmint, off, 64));

    // coverage: cells 0,2 share alignment (25600 % 256 == 0); cells 1,3 share
    const int m0 = (int)(((uintptr_t)r0 & 255) >> 2);
    const int m1 = (int)(((uintptr_t)(r0 + T) & 255) >> 2);
    const int cover_min = 64 - max(m0, m1);

    if (lmint >= cover_min) {
        // rare fallback: dense vectorized scan of the whole window (1600B).
        // Window floats = strip0 (cells 0,1: 200 floats at r0) + strip1
        // (cells 2,3: 200 floats at r0 + W*T). 100 float4 total.
        int fb = T;
        #pragma unroll
        for (int j = 0; j < 2; ++j) {
            const int idx = j * 64 + lane;       // float4 index in window
            if (idx < 100) {
                const int strip = (idx >= 50) ? 1 : 0;
                const int k = idx - 50 * strip;  // float4 within strip
                const float4 u = *(const float4*)(r0 + (size_t)strip * W * T + k * 4);
                const int f = k * 4;             // local float index (no t-boundary crossing: 100%4==0)
                const int tb = (f >= 100) ? f - 100 : f;
                if (u.x > 0.0f) fb = min(fb, tb + 0);
                if (u.y > 0.0f) fb = min(fb, tb + 1);
                if (u.z > 0.0f) fb = min(fb, tb + 2);
                if (u.w > 0.0f) fb = min(fb, tb + 3);
            }
        }
        #pragma unroll
        for (int off = 32; off >= 1; off >>= 1)
            fb = min(fb, __shfl_xor(fb, off, 64));
        lmint = fb;
    }

    // write one-hot: 25 float4 = contiguous 400B
    float* __restrict__ o = out + (size_t)p * T;
    if (lane < 25) {
        const int tw = lane * 4;
        float4 w4;
        w4.x = (tw     == lmint) ? 1.0f : 0.0f;
        w4.y = (tw + 1 == lmint) ? 1.0f : 0.0f;
        w4.z = (tw + 2 == lmint) ? 1.0f : 0.0f;
        w4.w = (tw + 3 == lmint) ? 1.0f : 0.0f;
        *reinterpret_cast<float4*>(o + tw) = w4;
    }
}

extern "C" void kernel_launch(void* const* d_in, const int* in_sizes, int n_in,
                              void* d_out, int out_size, void* d_ws, size_t ws_size,
                              hipStream_t stream) {
    const float* x = (const float*)d_in[0];
    float* out = (float*)d_out;

    const int B = 4, C = 32, OH = 32, OW = 32;
    const int n_pix = B * C * OH * OW;          // 131072
    const int blocks = n_pix / 4;               // 1 window/wave, 4 waves/block

    snn_wta_kernel<<<blocks, 256, 0, stream>>>(x, out, n_pix);
}

// Round 5
// 22.077 us; speedup vs baseline: 1.4427x; 1.4427x over previous
//
#include <hip/hip_runtime.h>

// SNNMaxPool2d winner-take-all forward, line-aligned sparse probe + tiered
// fallback. x: [B=4, C=32, H=64, W=64, T=100] f32 spikes.
// out: [4,32,32,32,100] one-hot of earliest spiking t per 2x2/stride-2 window.
//
// One wave64 handles TWO windows (half-wave each). Per window: 4 cells x 8
// lanes x float4 = each cell's probe is the 128B-aligned line containing its
// t=0. Timing-fit across R1-R4 indicates ~256B effective HBM fetch granule;
// the 4 cell probes hit exactly 4 granules/window (cells are 400B apart ->
// never share a granule), which is the read floor for this problem.
// Tier-2 (~5% of windows): one more 128B line at +32 floats (usually the
// other half of an already-fetched granule), extending coverage by 32 steps.
// Dense scan remains only for P(no spike in cover+32 steps) ~ 3e-7.

#define T_DIM 100

__global__ __launch_bounds__(256) void snn_wta_kernel(
    const float* __restrict__ x, float* __restrict__ out, int n_pix)
{
    const int T = T_DIM;
    const int C = 32, H = 64, W = 64, OH = 32, OW = 32;

    const int wave = threadIdx.x >> 6;   // 0..3
    const int lane = threadIdx.x & 63;
    const int half = lane >> 5;          // which window of the pair
    const int q2   = lane & 31;          // lane within half
    const int cell = q2 >> 3;            // 0..3 window cell
    const int q    = q2 & 7;             // lane within cell (8 x float4 = 128B)

    const int p = (blockIdx.x * 4 + wave) * 2 + half;
    if (p >= n_pix) return;              // grid exact; safety

    const int ow = p & (OW - 1);
    int tmp = p >> 5;
    const int oh = tmp & (OH - 1);
    tmp >>= 5;
    const int c = tmp & (C - 1);
    const int b = tmp >> 5;

    const size_t base0 = ((((size_t)b * C + c) * H + oh * 2) * W + ow * 2) * T;
    const float* __restrict__ r0 = x + base0;          // (h,w) then (h,w+1)
    const float* __restrict__ A  = r0
        + ((cell & 2) ? (size_t)W * T : 0)
        + ((cell & 1) ? T : 0);

    // tier-1 probe: the whole 128B line containing this cell's t=0
    const float* __restrict__ Ad =
        (const float*)((uintptr_t)A & ~(uintptr_t)127);
    const int moff = (int)(((uintptr_t)A & 127) >> 2);   // junk floats before t=0
    const float4 v = *(const float4*)(Ad + q * 4);
    const int t0 = q * 4 - moff;                         // in [-31, 31]

    int lmint = T;
    if (t0 + 0 >= 0 && v.x > 0.0f) lmint = min(lmint, t0 + 0);
    if (t0 + 1 >= 0 && v.y > 0.0f) lmint = min(lmint, t0 + 1);
    if (t0 + 2 >= 0 && v.z > 0.0f) lmint = min(lmint, t0 + 2);
    if (t0 + 3 >= 0 && v.w > 0.0f) lmint = min(lmint, t0 + 3);

    // half-wave (32-lane) min-reduce: xor offsets <32 stay within the half
    #pragma unroll
    for (int off = 16; off >= 1; off >>= 1)
        lmint = min(lmint, __shfl_xor(lmint, off, 64));

    // guaranteed-covered prefix across all 4 cells:
    // cells 0,2 share alignment (25600B = 200 lines); cells 1,3 share (+400B)
    const int m0 = (int)(((uintptr_t)r0 & 127) >> 2);
    const int m1 = (int)(((uintptr_t)(r0 + T) & 127) >> 2);
    const int cover1 = 32 - max(m0, m1);

    const bool need = (lmint >= cover1);        // half-uniform
    if (__any(need)) {                          // wave-uniform entry
        if (need) {
            // tier-2: next 128B line, covers t in [cover, cover+32) per cell
            const float4 u = *(const float4*)(Ad + 32 + q * 4);
            const int t1 = t0 + 32;             // >= 1 always
            if (u.x > 0.0f) lmint = min(lmint, t1 + 0);
            if (u.y > 0.0f) lmint = min(lmint, t1 + 1);
            if (u.z > 0.0f) lmint = min(lmint, t1 + 2);
            if (u.w > 0.0f) lmint = min(lmint, t1 + 3);
        }
        #pragma unroll
        for (int off = 16; off >= 1; off >>= 1)
            lmint = min(lmint, __shfl_xor(lmint, off, 64));

        if (lmint >= cover1 + 32) {             // half-uniform, ~3e-7
            int fb = T;
            for (int t = q; t < T; t += 8) {
                if (A[t] > 0.0f) { fb = t; break; }
            }
            lmint = fb;
            #pragma unroll
            for (int off = 16; off >= 1; off >>= 1)
                lmint = min(lmint, __shfl_xor(lmint, off, 64));
        }
    }

    // write one-hot: 25 float4 per window, contiguous 400B
    float* __restrict__ o = out + (size_t)p * T;
    if (q2 < 25) {
        const int tw = q2 * 4;
        float4 w4;
        w4.x = (tw     == lmint) ? 1.0f : 0.0f;
        w4.y = (tw + 1 == lmint) ? 1.0f : 0.0f;
        w4.z = (tw + 2 == lmint) ? 1.0f : 0.0f;
        w4.w = (tw + 3 == lmint) ? 1.0f : 0.0f;
        *reinterpret_cast<float4*>(o + tw) = w4;
    }
}

extern "C" void kernel_launch(void* const* d_in, const int* in_sizes, int n_in,
                              void* d_out, int out_size, void* d_ws, size_t ws_size,
                              hipStream_t stream) {
    const float* x = (const float*)d_in[0];
    float* out = (float*)d_out;

    const int B = 4, C = 32, OH = 32, OW = 32;
    const int n_pix = B * C * OH * OW;          // 131072
    const int blocks = n_pix / 8;               // 2 windows/wave, 4 waves/block

    snn_wta_kernel<<<blocks, 256, 0, stream>>>(x, out, n_pix);
}